// Round 16
// baseline (552.843 us; speedup 1.0000x reference)
//
#include <hip/hip_runtime.h>
#include <hip/hip_cooperative_groups.h>
#include <hip/hip_fp8.h>
#include <math.h>

#define N_NODES 100000
#define N_EDGES 1600000
#define F_IN    4
#define HID     128
#define N_CLS   5
#define N_GRAPH 256

#define BSHIFT   9
#define BSIZE    512
#define NBUK     196            // ceil(100000 / 512)
#define NCHUNK   200
#define CHUNK    8000           // 200 * 8000 = 1.6M exactly
#define BUKPAD   8192           // per-bucket pad capacity (>= 512*15)

namespace cg = cooperative_groups;

typedef _Float16 f16;
typedef _Float16 f16x8 __attribute__((ext_vector_type(8)));
typedef float f32x4 __attribute__((ext_vector_type(4)));

// decode 4-byte edge record: [src:17 | coef-f16-positive:15]; record 0 == dummy (src 0, coef 0)
__device__ __forceinline__ float rec_coef(unsigned r) {
    return (float)__builtin_bit_cast(_Float16, (unsigned short)(r & 0x7FFFu));
}

__device__ __forceinline__ float2 fp8x2_to_f32x2(unsigned short raw) {
    __hip_fp8x2_e4m3 t;
    t.__x = raw;
    return static_cast<float2>(t);
}

// 8 fp8 values (uint2) -> fma into acc[0..7] with coefficient c
__device__ __forceinline__ void fma8(float c, uint2 v, float* acc) {
    float2 p0 = fp8x2_to_f32x2((unsigned short)(v.x & 0xFFFFu));
    float2 p1 = fp8x2_to_f32x2((unsigned short)(v.x >> 16));
    float2 p2 = fp8x2_to_f32x2((unsigned short)(v.y & 0xFFFFu));
    float2 p3 = fp8x2_to_f32x2((unsigned short)(v.y >> 16));
    acc[0] = fmaf(c, p0.x, acc[0]); acc[1] = fmaf(c, p0.y, acc[1]);
    acc[2] = fmaf(c, p1.x, acc[2]); acc[3] = fmaf(c, p1.y, acc[3]);
    acc[4] = fmaf(c, p2.x, acc[4]); acc[5] = fmaf(c, p2.y, acc[5]);
    acc[6] = fmaf(c, p3.x, acc[6]); acc[7] = fmaf(c, p3.y, acc[7]);
}

// ================= ONE cooperative kernel: entire CSR build + W pack =================
// Grid = 392 blocks x 256. Phases separated by grid.sync():
//  A: blocks 0..199 chunk-histogram dst -> C; blocks 200..391 pack W2/3/4 -> Wp
//  B: block 0: per-bucket chunk-offset scan + bucket bases
//  C: blocks 0..199 scatter packed (src,dstLow) records into bucket-grouped bkt[]
//  D: blocks 0..195 per-bucket hist -> deg, dinv, rowptrP (closed-form padded bases)
//  E: blocks 0..195 pad-init + scatter + coef -> final edges[]
__global__ __launch_bounds__(256) void k_build_all(const int* __restrict__ src,
                                                   const int* __restrict__ dst,
                                                   int* __restrict__ C, int* __restrict__ Off,
                                                   int* __restrict__ bbase,
                                                   unsigned* __restrict__ bkt,
                                                   int* __restrict__ deg, float* __restrict__ dinv,
                                                   int* __restrict__ rowptrP,
                                                   unsigned* __restrict__ edges,
                                                   const float* __restrict__ W2,
                                                   const float* __restrict__ W3,
                                                   const float* __restrict__ W4,
                                                   f16* __restrict__ Wp) {
    cg::grid_group grid = cg::this_grid();
    __shared__ int sm1[BSIZE];
    __shared__ int sm2[BSIZE];
    int t = threadIdx.x;
    int blk = blockIdx.x;

    // ---- phase A ----
    if (blk < NCHUNK) {
        if (t < NBUK) sm1[t] = 0;
        __syncthreads();
        int base = blk * CHUNK;
#pragma unroll
        for (int it = 0; it < 32; ++it) {
            int idx = it * 256 + t;
            if (idx < CHUNK) atomicAdd(&sm1[dst[base + idx] >> BSHIFT], 1);
        }
        __syncthreads();
        if (t < NBUK) C[blk * NBUK + t] = sm1[t];
    } else {
        int idx = (blk - NCHUNK) * 256 + t;   // 0..49151
        int which = idx >> 14;
        int r = idx & 16383;
        const float* W = (which == 0) ? W2 : (which == 1) ? W3 : W4;
        int j  = r & 7;
        int L  = (r >> 3) & 63;
        int ks = (r >> 9) & 3;
        int ct = r >> 11;
        Wp[idx] = (f16)W[(ks * 32 + (L >> 4) * 8 + j) * HID + ct * 16 + (L & 15)];
    }
    grid.sync();

    // ---- phase B (block 0 only) ----
    if (blk == 0) {
        int b = t;
        int tot = 0;
        if (b < NBUK) {
            for (int c = 0; c < NCHUNK; ++c) {
                Off[c * NBUK + b] = tot;
                tot += C[c * NBUK + b];
            }
        }
        sm1[b] = (b < NBUK) ? tot : 0;
        __syncthreads();
        for (int off = 1; off < 256; off <<= 1) {
            int v = (b >= off) ? sm1[b - off] : 0;
            __syncthreads();
            sm1[b] += v;
            __syncthreads();
        }
        if (b < NBUK) bbase[b] = sm1[b] - tot;   // exclusive
        if (b == 0) bbase[NBUK] = N_EDGES;
    }
    grid.sync();

    // ---- phase C ----
    if (blk < NCHUNK) {
        if (t < NBUK) sm1[t] = bbase[t] + Off[blk * NBUK + t];
        __syncthreads();
        int base = blk * CHUNK;
#pragma unroll
        for (int it = 0; it < 32; ++it) {
            int idx = it * 256 + t;
            if (idx < CHUNK) {
                int s = src[base + idx], d = dst[base + idx];
                int b = d >> BSHIFT;
                int p = atomicAdd(&sm1[b], 1);
                bkt[p] = ((unsigned)s << BSHIFT) | (unsigned)(d & (BSIZE - 1));
            }
        }
    }
    grid.sync();

    // ---- phase D ----
    if (blk < NBUK) {
        int b = blk;
        int s0 = bbase[b], s1 = bbase[b + 1];
        sm1[t] = 0; sm1[t + 256] = 0;
        __syncthreads();
        for (int e = s0 + t; e < s1; e += 256) atomicAdd(&sm1[bkt[e] & (BSIZE - 1)], 1);
        __syncthreads();
        int h0 = sm1[t], h1 = sm1[t + 256];
        int p0 = ((h0 + 15) >> 4) << 4;
        int p1 = ((h1 + 15) >> 4) << 4;
        sm2[t] = p0; sm2[t + 256] = p1;
        __syncthreads();
        for (int off = 1; off < BSIZE; off <<= 1) {
            int i1 = t + 256;
            int v0 = (t >= off) ? sm2[t - off] : 0;
            int v1 = (i1 >= off) ? sm2[i1 - off] : 0;
            __syncthreads();
            sm2[t] += v0; sm2[i1] += v1;
            __syncthreads();
        }
        int base = s0 + b * BUKPAD;          // closed-form padded bucket base
        int n0 = b * BSIZE + t, n1 = n0 + 256;
        if (n0 < N_NODES) {
            deg[n0] = h0;
            dinv[n0] = rsqrtf((float)h0 + 1.0f);
            rowptrP[n0] = base + sm2[t] - p0;
        }
        if (n1 < N_NODES) {
            deg[n1] = h1;
            dinv[n1] = rsqrtf((float)h1 + 1.0f);
            rowptrP[n1] = base + sm2[t + 256] - p1;
        }
    }
    grid.sync();

    // ---- phase E ----
    if (blk < NBUK) {
        int b = blk;
        int s0 = bbase[b], s1 = bbase[b + 1];
        int n0 = b * BSIZE + t, n1 = n0 + 256;
        int d0 = (n0 < N_NODES) ? deg[n0] : 0;
        int d1 = (n1 < N_NODES) ? deg[n1] : 0;
        int r0 = (n0 < N_NODES) ? rowptrP[n0] : 0;
        int r1 = (n1 < N_NODES) ? rowptrP[n1] : 0;
        float* dv = (float*)sm2;
        dv[t] = (n0 < N_NODES) ? dinv[n0] : 0.f;
        dv[t + 256] = (n1 < N_NODES) ? dinv[n1] : 0.f;
        sm1[t] = r0; sm1[t + 256] = r1;
        int p0 = ((d0 + 15) >> 4) << 4;
        int p1 = ((d1 + 15) >> 4) << 4;
        for (int i = d0; i < p0; ++i) edges[r0 + i] = 0;
        for (int i = d1; i < p1; ++i) edges[r1 + i] = 0;
        __syncthreads();
        for (int e = s0 + t; e < s1; e += 256) {
            unsigned r = bkt[e];
            int dl = (int)(r & (BSIZE - 1));
            int s = (int)(r >> BSHIFT);
            int p = atomicAdd(&sm1[dl], 1);
            float c = dv[dl] * dinv[s];
            unsigned short cb = __builtin_bit_cast(unsigned short, (f16)c);
            edges[p] = ((unsigned)s << 15) | (unsigned)(cb & 0x7FFFu);
        }
    }
}

// ---------------- FUSED layer 1: wave-parallel Agg(x) + (Nx4)@(4x128) GEMM, fp8 out ---------
__global__ __launch_bounds__(256) void k_aggx1(const float4* __restrict__ x,
                                               const int* __restrict__ rowptrP,
                                               const int* __restrict__ deg,
                                               const unsigned* __restrict__ edges,
                                               const float* __restrict__ dinv,
                                               const float* __restrict__ W1, const float* __restrict__ b1,
                                               unsigned* __restrict__ hA) {
    __shared__ float4 sxa[16];
    __shared__ float sW[4 * HID];
    __shared__ float sb[HID];
    int t = threadIdx.x;
    sW[t] = W1[t];
    sW[t + 256] = W1[t + 256];
    if (t < HID) sb[t] = b1[t];
    int grp = t >> 4;             // 0..15 local node
    int l = t & 15;
    int node = blockIdx.x * 16 + grp;   // grid 6250 -> exact
    int beg = rowptrP[node];
    int end = beg + (((deg[node] + 15) >> 4) << 4);
    float ax = 0.f, ay = 0.f, az = 0.f, aw = 0.f;
    for (int e = beg + l; e < end; e += 16) {
        unsigned r = edges[e];
        float c = rec_coef(r);
        float4 v = x[r >> 15];
        ax = fmaf(c, v.x, ax); ay = fmaf(c, v.y, ay);
        az = fmaf(c, v.z, az); aw = fmaf(c, v.w, aw);
    }
#pragma unroll
    for (int off = 1; off < 16; off <<= 1) {
        ax += __shfl_xor(ax, off, 64);
        ay += __shfl_xor(ay, off, 64);
        az += __shfl_xor(az, off, 64);
        aw += __shfl_xor(aw, off, 64);
    }
    if (l == 0) {
        float di = dinv[node];
        float c0 = di * di;
        float4 xv = x[node];
        sxa[grp] = make_float4(fmaf(c0, xv.x, ax), fmaf(c0, xv.y, ay),
                               fmaf(c0, xv.z, az), fmaf(c0, xv.w, aw));
    }
    __syncthreads();

    int node0 = blockIdx.x * 16;
#pragma unroll
    for (int it = 0; it < 2; ++it) {
        int id = it * 256 + t;       // 512 units = 16 nodes x 32 col-groups
        int n = id >> 5;
        int g = id & 31;
        float4 a = sxa[n];
        float c[4];
#pragma unroll
        for (int j = 0; j < 4; ++j) {
            int col = g * 4 + j;
            float v = sb[col];
            v = fmaf(a.x, sW[col],           v);
            v = fmaf(a.y, sW[HID + col],     v);
            v = fmaf(a.z, sW[2 * HID + col], v);
            v = fmaf(a.w, sW[3 * HID + col], v);
            c[j] = fmaxf(v, 0.0f);
        }
        unsigned lo = __hip_fp8x2_e4m3(make_float2(c[0], c[1])).__x;
        unsigned hi = __hip_fp8x2_e4m3(make_float2(c[2], c[3])).__x;
        hA[(node0 + n) * 32 + g] = lo | (hi << 16);
    }
}

// ---------------- FUSED layers 2..4: Agg (fp8, wave/node) -> LDS -> MFMA GEMM, fp8 out ------
__global__ __launch_bounds__(1024, 8) void k_aggemm8(const unsigned* __restrict__ h8,
                                                     const int* __restrict__ rowptrP,
                                                     const int* __restrict__ deg,
                                                     const unsigned* __restrict__ edges,
                                                     const float* __restrict__ dinv,
                                                     const f16* __restrict__ Wp,
                                                     const float* __restrict__ bias,
                                                     unsigned char* __restrict__ out8) {
    __shared__ f16 S[16 * HID];   // 4 KB strip, rows XOR-swizzled at dword granularity
    int wave = threadIdx.x >> 6;        // local node 0..15
    int lane = threadIdx.x & 63;
    int node0 = blockIdx.x * 16;
    int node = node0 + wave;
    int g = lane >> 4;
    int l = lane & 15;
    int beg = rowptrP[node];
    int end = beg + (((deg[node] + 15) >> 4) << 4);
    const char* hp = (const char*)h8 + l * 8;

    float acc[8];
    {
        float di = dinv[node];
        float c0 = (g == 0) ? di * di : 0.0f;
        uint2 v = *(const uint2*)(hp + ((size_t)node << 7));
        float2 p0 = fp8x2_to_f32x2((unsigned short)(v.x & 0xFFFFu));
        float2 p1 = fp8x2_to_f32x2((unsigned short)(v.x >> 16));
        float2 p2 = fp8x2_to_f32x2((unsigned short)(v.y & 0xFFFFu));
        float2 p3 = fp8x2_to_f32x2((unsigned short)(v.y >> 16));
        acc[0] = c0 * p0.x; acc[1] = c0 * p0.y;
        acc[2] = c0 * p1.x; acc[3] = c0 * p1.y;
        acc[4] = c0 * p2.x; acc[5] = c0 * p2.y;
        acc[6] = c0 * p3.x; acc[7] = c0 * p3.y;
    }

    for (int e = beg; e < end; e += 16) {
        unsigned rec16 = edges[e + l];
#pragma unroll
        for (int i = 0; i < 4; ++i) {
            unsigned rec = __shfl(rec16, i * 4 + g, 64);
            float c = rec_coef(rec);
            uint2 v = *(const uint2*)(hp + ((rec >> 8) & 0xFFFFFF80u));
            fma8(c, v, acc);
        }
    }

#pragma unroll
    for (int j = 0; j < 8; ++j) {
        acc[j] += __shfl_xor(acc[j], 16, 64);
        acc[j] += __shfl_xor(acc[j], 32, 64);
    }
    if (lane < 16) {
        f16x8 o;
#pragma unroll
        for (int j = 0; j < 8; ++j) o[j] = (f16)acc[j];
        int dw = (l * 4) ^ ((wave & 7) << 2);       // dword offset within row, swizzled
        *(f16x8*)&S[wave * HID + dw * 2] = o;
    }
    __syncthreads();

    // GEMM phase: waves 0..7 each handle column tile t = wave
    if (wave < 8) {
        int t = wave;
        int m = lane & 15;
        int q = lane >> 4;
        f32x4 c4 = (f32x4){0.f, 0.f, 0.f, 0.f};
#pragma unroll
        for (int ks = 0; ks < 4; ++ks) {
            int dw = (ks * 16 + q * 4) ^ ((m & 7) << 2);
            f16x8 a = *(const f16x8*)&S[m * HID + dw * 2];
            f16x8 b = *(const f16x8*)(Wp + ((size_t)(t * 4 + ks) * 64 + lane) * 8);
            c4 = __builtin_amdgcn_mfma_f32_16x16x32_f16(a, b, c4, 0, 0, 0);
        }
        float bb = bias[t * 16 + m];
#pragma unroll
        for (int r = 0; r < 4; ++r) {
            float val = fmaxf(c4[r] + bb, 0.0f);
            int row = node0 + q * 4 + r;
            out8[(size_t)row * HID + t * 16 + m] = ((__hip_fp8_e4m3)val).__x;
        }
    }
}

// ---------------- pooling + head, single kernel: one block per graph ------------------------
__device__ __forceinline__ int lower_bound_batch(const int* __restrict__ batch, int val) {
    int lo = 0, hi = N_NODES;
    while (lo < hi) { int m = (lo + hi) >> 1; if (batch[m] < val) lo = m + 1; else hi = m; }
    return lo;
}

__global__ __launch_bounds__(512) void k_poolh(const unsigned char* __restrict__ h8,
                                               const int* __restrict__ batch,
                                               const float* __restrict__ Wl, const float* __restrict__ bl,
                                               float* __restrict__ out) {
    __shared__ float sp[4][HID];
    __shared__ float sg[HID];
    int g = blockIdx.x;
    int s = threadIdx.x >> 7;    // segment 0..3
    int f = threadIdx.x & 127;
    int beg = lower_bound_batch(batch, g);
    int end = lower_bound_batch(batch, g + 1);
    int len = end - beg;
    int sb = beg + (int)(((long long)len * s) / 4);
    int se = beg + (int)(((long long)len * (s + 1)) / 4);
    float acc = 0.0f;
    for (int i = sb; i < se; ++i) {
        __hip_fp8_e4m3 v;
        v.__x = h8[(size_t)i * HID + f];
        acc += (float)v;
    }
    sp[s][f] = acc;
    __syncthreads();
    if (s == 0) sg[f] = (sp[0][f] + sp[1][f] + sp[2][f] + sp[3][f]) / fmaxf((float)len, 1.0f);
    __syncthreads();
    if (threadIdx.x < N_CLS) {
        int c = threadIdx.x;
        float v = bl[c];
        for (int k = 0; k < HID; ++k) v = fmaf(sg[k], Wl[k * N_CLS + c], v);
        out[g * N_CLS + c] = 1.0f / (1.0f + expf(-v));
    }
}

extern "C" void kernel_launch(void* const* d_in, const int* in_sizes, int n_in,
                              void* d_out, int out_size, void* d_ws, size_t ws_size,
                              hipStream_t stream) {
    const float* x     = (const float*)d_in[0];
    const int*   ei    = (const int*)d_in[1];
    const int*   batch = (const int*)d_in[2];
    const float* W1 = (const float*)d_in[3];  const float* b1 = (const float*)d_in[4];
    const float* W2 = (const float*)d_in[5];  const float* b2 = (const float*)d_in[6];
    const float* W3 = (const float*)d_in[7];  const float* b3 = (const float*)d_in[8];
    const float* W4 = (const float*)d_in[9];  const float* b4 = (const float*)d_in[10];
    const float* Wl = (const float*)d_in[11]; const float* bl = (const float*)d_in[12];
    float* out = (float*)d_out;

    const size_t EPAD = (size_t)N_EDGES + (size_t)NBUK * BUKPAD;   // 1.6M + 196*8192

    char* p = (char*)d_ws;
    auto alloc = [&](size_t bytes) { char* r = p; p += (bytes + 255) & ~(size_t)255; return (void*)r; };
    int*      C       = (int*)     alloc((size_t)NCHUNK * NBUK * 4);
    int*      Off     = (int*)     alloc((size_t)NCHUNK * NBUK * 4);
    int*      bbase   = (int*)     alloc((size_t)(NBUK + 1) * 4);
    unsigned* bkt     = (unsigned*)alloc((size_t)N_EDGES * 4);
    int*      deg     = (int*)     alloc((size_t)N_NODES * 4);
    int*      rowptrP = (int*)     alloc((size_t)(N_NODES + 1) * 4);
    float*    dinv    = (float*)   alloc((size_t)N_NODES * 4);
    unsigned* edges   = (unsigned*)alloc(EPAD * 4);
    unsigned* hA      = (unsigned*)alloc((size_t)N_NODES * HID);      // fp8 ping
    unsigned* hC      = (unsigned*)alloc((size_t)N_NODES * HID);      // fp8 pong
    f16*      Wp      = (f16*)     alloc((size_t)3 * HID * HID * 2);
    f16*      Wp2 = Wp;
    f16*      Wp3 = Wp + HID * HID;
    f16*      Wp4 = Wp + 2 * HID * HID;

    const int* srcv = ei;              // edge_index[0]
    const int* dstv = ei + N_EDGES;    // edge_index[1]

    // entire CSR build + W pack: ONE cooperative kernel (5 phases, grid.sync between)
    void* cargs[] = {(void*)&srcv, (void*)&dstv, (void*)&C, (void*)&Off, (void*)&bbase,
                     (void*)&bkt, (void*)&deg, (void*)&dinv, (void*)&rowptrP, (void*)&edges,
                     (void*)&W2, (void*)&W3, (void*)&W4, (void*)&Wp};
    hipLaunchCooperativeKernel((void*)k_build_all, dim3(NCHUNK + 192), dim3(256), cargs, 0, stream);

    // layer 1: fused wave-parallel Agg(x) + (Nx4)@(4x128) GEMM, fp8 out
    k_aggx1<<<N_NODES / 16, 256, 0, stream>>>((const float4*)x, rowptrP, deg, edges, dinv, W1, b1, hA);

    // layers 2..4: fused Agg (fp8 gather, full TLP) + MFMA GEMM (+bias, ReLU), fp8 out
    const int fgrid = N_NODES / 16;   // 6250, 1024-thread blocks
    k_aggemm8<<<fgrid, 1024, 0, stream>>>(hA, rowptrP, deg, edges, dinv, Wp2, b2, (unsigned char*)hC);
    k_aggemm8<<<fgrid, 1024, 0, stream>>>(hC, rowptrP, deg, edges, dinv, Wp3, b3, (unsigned char*)hA);
    k_aggemm8<<<fgrid, 1024, 0, stream>>>(hA, rowptrP, deg, edges, dinv, Wp4, b4, (unsigned char*)hC);

    // mean-pool + head, one block per graph
    k_poolh<<<N_GRAPH, 512, 0, stream>>>((const unsigned char*)hC, batch, Wl, bl, out);
}

// Round 17
// 361.582 us; speedup vs baseline: 1.5290x; 1.5290x over previous
//
#include <hip/hip_runtime.h>
#include <hip/hip_fp8.h>
#include <math.h>

#define N_NODES 100000
#define N_EDGES 1600000
#define F_IN    4
#define HID     128
#define N_CLS   5
#define N_GRAPH 256

#define BSHIFT   9
#define BSIZE    512
#define NBUK     196            // ceil(100000 / 512)
#define NCHUNK   200
#define CHUNK    8000           // 200 * 8000 = 1.6M exactly
#define BUKPAD   8192           // per-bucket pad capacity (>= 512*15)

typedef _Float16 f16;
typedef _Float16 f16x8 __attribute__((ext_vector_type(8)));
typedef float f32x4 __attribute__((ext_vector_type(4)));

// decode 4-byte edge record: [src:17 | coef-f16-positive:15]; record 0 == dummy (src 0, coef 0)
__device__ __forceinline__ float rec_coef(unsigned r) {
    return (float)__builtin_bit_cast(_Float16, (unsigned short)(r & 0x7FFFu));
}

__device__ __forceinline__ float2 fp8x2_to_f32x2(unsigned short raw) {
    __hip_fp8x2_e4m3 t;
    t.__x = raw;
    return static_cast<float2>(t);
}

// 8 fp8 values (uint2) -> fma into acc[0..7] with coefficient c
__device__ __forceinline__ void fma8(float c, uint2 v, float* acc) {
    float2 p0 = fp8x2_to_f32x2((unsigned short)(v.x & 0xFFFFu));
    float2 p1 = fp8x2_to_f32x2((unsigned short)(v.x >> 16));
    float2 p2 = fp8x2_to_f32x2((unsigned short)(v.y & 0xFFFFu));
    float2 p3 = fp8x2_to_f32x2((unsigned short)(v.y >> 16));
    acc[0] = fmaf(c, p0.x, acc[0]); acc[1] = fmaf(c, p0.y, acc[1]);
    acc[2] = fmaf(c, p1.x, acc[2]); acc[3] = fmaf(c, p1.y, acc[3]);
    acc[4] = fmaf(c, p2.x, acc[4]); acc[5] = fmaf(c, p2.y, acc[5]);
    acc[6] = fmaf(c, p3.x, acc[6]); acc[7] = fmaf(c, p3.y, acc[7]);
}

// ---------------- step 1: per-(chunk,bucket) counts via LDS histogram + W pack (merged) -----
__global__ __launch_bounds__(256) void k_bcp(const int* __restrict__ dst, int* __restrict__ C,
                                             const float* __restrict__ W2, const float* __restrict__ W3,
                                             const float* __restrict__ W4, f16* __restrict__ Wp) {
    int t = threadIdx.x;
    if (blockIdx.x < NCHUNK) {
        __shared__ int cnt[NBUK];
        if (t < NBUK) cnt[t] = 0;
        __syncthreads();
        int base = blockIdx.x * CHUNK;
#pragma unroll
        for (int it = 0; it < 32; ++it) {
            int idx = it * 256 + t;
            if (idx < CHUNK) atomicAdd(&cnt[dst[base + idx] >> BSHIFT], 1);
        }
        __syncthreads();
        if (t < NBUK) C[blockIdx.x * NBUK + t] = cnt[t];
    } else {
        int idx = (blockIdx.x - NCHUNK) * 256 + t;   // 0..49151
        int which = idx >> 14;
        int r = idx & 16383;
        const float* W = (which == 0) ? W2 : (which == 1) ? W3 : W4;
        int j  = r & 7;
        int L  = (r >> 3) & 63;
        int ks = (r >> 9) & 3;
        int ct = r >> 11;
        Wp[idx] = (f16)W[(ks * 32 + (L >> 4) * 8 + j) * HID + ct * 16 + (L & 15)];
    }
}

// ---------------- step 2: offsets. Off[c][b] = prefix over chunks; bbase = bucket bases -----
__global__ __launch_bounds__(256) void k_bscan(const int* __restrict__ C, int* __restrict__ Off,
                                               int* __restrict__ bbase) {
    __shared__ int s[256];
    int b = threadIdx.x;
    int tot = 0;
    if (b < NBUK) {
        for (int c = 0; c < NCHUNK; ++c) {
            Off[c * NBUK + b] = tot;
            tot += C[c * NBUK + b];
        }
    }
    s[b] = (b < NBUK) ? tot : 0;
    __syncthreads();
    for (int off = 1; off < 256; off <<= 1) {
        int v = (b >= off) ? s[b - off] : 0;
        __syncthreads();
        s[b] += v;
        __syncthreads();
    }
    if (b < NBUK) bbase[b] = s[b] - tot;   // exclusive
    if (b == 0) bbase[NBUK] = N_EDGES;
}

// ---------------- step 3: scatter packed records into bucket-grouped array ------------------
// record: (src:17)<<9 | (dst & 511)
__global__ __launch_bounds__(256) void k_scatter(const int* __restrict__ src, const int* __restrict__ dst,
                                                 const int* __restrict__ Off, const int* __restrict__ bbase,
                                                 unsigned* __restrict__ bkt) {
    __shared__ int cur[NBUK];
    int t = threadIdx.x;
    if (t < NBUK) cur[t] = bbase[t] + Off[blockIdx.x * NBUK + t];
    __syncthreads();
    int base = blockIdx.x * CHUNK;
#pragma unroll
    for (int it = 0; it < 32; ++it) {
        int idx = it * 256 + t;
        if (idx < CHUNK) {
            int s = src[base + idx], d = dst[base + idx];
            int b = d >> BSHIFT;
            int p = atomicAdd(&cur[b], 1);
            bkt[p] = ((unsigned)s << BSHIFT) | (unsigned)(d & (BSIZE - 1));
        }
    }
}

// ---------------- step 4: per-bucket hist -> deg, dinv, rowBE {beg, padded end} -------------
__global__ __launch_bounds__(256) void k_build1(const unsigned* __restrict__ bkt,
                                                const int* __restrict__ bbase,
                                                int* __restrict__ deg, float* __restrict__ dinv,
                                                int2* __restrict__ rowBE) {
    __shared__ int hist[BSIZE], sc[BSIZE];
    int t = threadIdx.x, b = blockIdx.x;
    int s0 = bbase[b], s1 = bbase[b + 1];
    hist[t] = 0; hist[t + 256] = 0;
    __syncthreads();
    for (int e = s0 + t; e < s1; e += 256) atomicAdd(&hist[bkt[e] & (BSIZE - 1)], 1);
    __syncthreads();
    int p0 = ((hist[t] + 15) >> 4) << 4;
    int p1 = ((hist[t + 256] + 15) >> 4) << 4;
    sc[t] = p0; sc[t + 256] = p1;
    __syncthreads();
    for (int off = 1; off < BSIZE; off <<= 1) {
        int i0 = t, i1 = t + 256;
        int v0 = (i0 >= off) ? sc[i0 - off] : 0;
        int v1 = (i1 >= off) ? sc[i1 - off] : 0;
        __syncthreads();
        sc[i0] += v0; sc[i1] += v1;
        __syncthreads();
    }
    int base = s0 + b * BUKPAD;          // closed-form padded bucket base
    int n0 = b * BSIZE + t, n1 = n0 + 256;
    if (n0 < N_NODES) {
        deg[n0] = hist[t];
        dinv[n0] = rsqrtf((float)hist[t] + 1.0f);
        int beg = base + sc[t] - p0;
        rowBE[n0] = make_int2(beg, beg + p0);
    }
    if (n1 < N_NODES) {
        deg[n1] = hist[t + 256];
        dinv[n1] = rsqrtf((float)hist[t + 256] + 1.0f);
        int beg = base + sc[t + 256] - p1;
        rowBE[n1] = make_int2(beg, beg + p1);
    }
}

// ---------------- step 5: pad-init + scatter + coef into final edge records -----------------
__global__ __launch_bounds__(256) void k_fill2(const unsigned* __restrict__ bkt,
                                               const int* __restrict__ bbase,
                                               const int* __restrict__ deg,
                                               const float* __restrict__ dinv,
                                               const int2* __restrict__ rowBE,
                                               unsigned* __restrict__ edges) {
    __shared__ int cur[BSIZE];
    __shared__ float dv[BSIZE];
    int t = threadIdx.x, b = blockIdx.x;
    int s0 = bbase[b], s1 = bbase[b + 1];
    int n0 = b * BSIZE + t, n1 = n0 + 256;
    int d0 = (n0 < N_NODES) ? deg[n0] : 0;
    int d1 = (n1 < N_NODES) ? deg[n1] : 0;
    int2 be0 = (n0 < N_NODES) ? rowBE[n0] : make_int2(0, 0);
    int2 be1 = (n1 < N_NODES) ? rowBE[n1] : make_int2(0, 0);
    dv[t] = (n0 < N_NODES) ? dinv[n0] : 0.f;
    dv[t + 256] = (n1 < N_NODES) ? dinv[n1] : 0.f;
    cur[t] = be0.x; cur[t + 256] = be1.x;
    // init pad tails to dummy records (record 0 = src 0, coef 0)
    for (int i = be0.x + d0; i < be0.y; ++i) edges[i] = 0;
    for (int i = be1.x + d1; i < be1.y; ++i) edges[i] = 0;
    __syncthreads();
    for (int e = s0 + t; e < s1; e += 256) {
        unsigned r = bkt[e];
        int dl = (int)(r & (BSIZE - 1));
        int s = (int)(r >> BSHIFT);
        int p = atomicAdd(&cur[dl], 1);
        float c = dv[dl] * dinv[s];
        unsigned short cb = __builtin_bit_cast(unsigned short, (f16)c);
        edges[p] = ((unsigned)s << 15) | (unsigned)(cb & 0x7FFFu);
    }
}

// ---------------- FUSED layer 1: wave-parallel Agg(x) + (Nx4)@(4x128) GEMM, fp8 out ---------
__global__ __launch_bounds__(256) void k_aggx1(const float4* __restrict__ x,
                                               const int2* __restrict__ rowBE,
                                               const unsigned* __restrict__ edges,
                                               const float* __restrict__ dinv,
                                               const float* __restrict__ W1, const float* __restrict__ b1,
                                               unsigned* __restrict__ hA) {
    __shared__ float4 sxa[16];
    __shared__ float sW[4 * HID];
    __shared__ float sb[HID];
    int t = threadIdx.x;
    sW[t] = W1[t];
    sW[t + 256] = W1[t + 256];
    if (t < HID) sb[t] = b1[t];
    int grp = t >> 4;             // 0..15 local node
    int l = t & 15;
    int node = blockIdx.x * 16 + grp;   // grid 6250 -> exact
    int2 be = rowBE[node];
    float ax = 0.f, ay = 0.f, az = 0.f, aw = 0.f;
    for (int e = be.x + l; e < be.y; e += 16) {
        unsigned r = edges[e];
        float c = rec_coef(r);
        float4 v = x[r >> 15];
        ax = fmaf(c, v.x, ax); ay = fmaf(c, v.y, ay);
        az = fmaf(c, v.z, az); aw = fmaf(c, v.w, aw);
    }
#pragma unroll
    for (int off = 1; off < 16; off <<= 1) {
        ax += __shfl_xor(ax, off, 64);
        ay += __shfl_xor(ay, off, 64);
        az += __shfl_xor(az, off, 64);
        aw += __shfl_xor(aw, off, 64);
    }
    if (l == 0) {
        float di = dinv[node];
        float c0 = di * di;
        float4 xv = x[node];
        sxa[grp] = make_float4(fmaf(c0, xv.x, ax), fmaf(c0, xv.y, ay),
                               fmaf(c0, xv.z, az), fmaf(c0, xv.w, aw));
    }
    __syncthreads();

    int node0 = blockIdx.x * 16;
#pragma unroll
    for (int it = 0; it < 2; ++it) {
        int id = it * 256 + t;       // 512 units = 16 nodes x 32 col-groups
        int n = id >> 5;
        int g = id & 31;
        float4 a = sxa[n];
        float c[4];
#pragma unroll
        for (int j = 0; j < 4; ++j) {
            int col = g * 4 + j;
            float v = sb[col];
            v = fmaf(a.x, sW[col],           v);
            v = fmaf(a.y, sW[HID + col],     v);
            v = fmaf(a.z, sW[2 * HID + col], v);
            v = fmaf(a.w, sW[3 * HID + col], v);
            c[j] = fmaxf(v, 0.0f);
        }
        unsigned lo = __hip_fp8x2_e4m3(make_float2(c[0], c[1])).__x;
        unsigned hi = __hip_fp8x2_e4m3(make_float2(c[2], c[3])).__x;
        hA[(node0 + n) * 32 + g] = lo | (hi << 16);
    }
}

// ---------------- FUSED layers 2..4: Agg (fp8, wave/node) -> LDS -> MFMA GEMM, fp8 out ------
__global__ __launch_bounds__(1024, 8) void k_aggemm8(const unsigned* __restrict__ h8,
                                                     const int2* __restrict__ rowBE,
                                                     const unsigned* __restrict__ edges,
                                                     const float* __restrict__ dinv,
                                                     const f16* __restrict__ Wp,
                                                     const float* __restrict__ bias,
                                                     unsigned char* __restrict__ out8) {
    __shared__ f16 S[16 * HID];   // 4 KB strip, rows XOR-swizzled at dword granularity
    int wave = threadIdx.x >> 6;        // local node 0..15
    int lane = threadIdx.x & 63;
    int node0 = blockIdx.x * 16;
    int node = node0 + wave;
    int g = lane >> 4;
    int l = lane & 15;
    int2 be = rowBE[node];
    const char* hp = (const char*)h8 + l * 8;

    float acc[8];
    {
        float di = dinv[node];
        float c0 = (g == 0) ? di * di : 0.0f;
        uint2 v = *(const uint2*)(hp + ((size_t)node << 7));
        float2 p0 = fp8x2_to_f32x2((unsigned short)(v.x & 0xFFFFu));
        float2 p1 = fp8x2_to_f32x2((unsigned short)(v.x >> 16));
        float2 p2 = fp8x2_to_f32x2((unsigned short)(v.y & 0xFFFFu));
        float2 p3 = fp8x2_to_f32x2((unsigned short)(v.y >> 16));
        acc[0] = c0 * p0.x; acc[1] = c0 * p0.y;
        acc[2] = c0 * p1.x; acc[3] = c0 * p1.y;
        acc[4] = c0 * p2.x; acc[5] = c0 * p2.y;
        acc[6] = c0 * p3.x; acc[7] = c0 * p3.y;
    }

    for (int e = be.x; e < be.y; e += 16) {
        unsigned rec16 = edges[e + l];
#pragma unroll
        for (int i = 0; i < 4; ++i) {
            unsigned rec = __shfl(rec16, i * 4 + g, 64);
            float c = rec_coef(rec);
            uint2 v = *(const uint2*)(hp + ((rec >> 8) & 0xFFFFFF80u));
            fma8(c, v, acc);
        }
    }

#pragma unroll
    for (int j = 0; j < 8; ++j) {
        acc[j] += __shfl_xor(acc[j], 16, 64);
        acc[j] += __shfl_xor(acc[j], 32, 64);
    }
    if (lane < 16) {
        f16x8 o;
#pragma unroll
        for (int j = 0; j < 8; ++j) o[j] = (f16)acc[j];
        int dw = (l * 4) ^ ((wave & 7) << 2);       // dword offset within row, swizzled
        *(f16x8*)&S[wave * HID + dw * 2] = o;
    }
    __syncthreads();

    // GEMM phase: waves 0..7 each handle column tile t = wave
    if (wave < 8) {
        int t = wave;
        int m = lane & 15;
        int q = lane >> 4;
        f32x4 c4 = (f32x4){0.f, 0.f, 0.f, 0.f};
#pragma unroll
        for (int ks = 0; ks < 4; ++ks) {
            int dw = (ks * 16 + q * 4) ^ ((m & 7) << 2);
            f16x8 a = *(const f16x8*)&S[m * HID + dw * 2];
            f16x8 b = *(const f16x8*)(Wp + ((size_t)(t * 4 + ks) * 64 + lane) * 8);
            c4 = __builtin_amdgcn_mfma_f32_16x16x32_f16(a, b, c4, 0, 0, 0);
        }
        float bb = bias[t * 16 + m];
#pragma unroll
        for (int r = 0; r < 4; ++r) {
            float val = fmaxf(c4[r] + bb, 0.0f);
            int row = node0 + q * 4 + r;
            out8[(size_t)row * HID + t * 16 + m] = ((__hip_fp8_e4m3)val).__x;
        }
    }
}

// ---------------- pooling + head, single kernel: one block per graph ------------------------
__device__ __forceinline__ int lower_bound_batch(const int* __restrict__ batch, int val) {
    int lo = 0, hi = N_NODES;
    while (lo < hi) { int m = (lo + hi) >> 1; if (batch[m] < val) lo = m + 1; else hi = m; }
    return lo;
}

__global__ __launch_bounds__(512) void k_poolh(const unsigned char* __restrict__ h8,
                                               const int* __restrict__ batch,
                                               const float* __restrict__ Wl, const float* __restrict__ bl,
                                               float* __restrict__ out) {
    __shared__ float sp[4][HID];
    __shared__ float sg[HID];
    int g = blockIdx.x;
    int s = threadIdx.x >> 7;    // segment 0..3
    int f = threadIdx.x & 127;
    int beg = lower_bound_batch(batch, g);
    int end = lower_bound_batch(batch, g + 1);
    int len = end - beg;
    int sb = beg + (int)(((long long)len * s) / 4);
    int se = beg + (int)(((long long)len * (s + 1)) / 4);
    float acc = 0.0f;
    for (int i = sb; i < se; ++i) {
        __hip_fp8_e4m3 v;
        v.__x = h8[(size_t)i * HID + f];
        acc += (float)v;
    }
    sp[s][f] = acc;
    __syncthreads();
    if (s == 0) sg[f] = (sp[0][f] + sp[1][f] + sp[2][f] + sp[3][f]) / fmaxf((float)len, 1.0f);
    __syncthreads();
    if (threadIdx.x < N_CLS) {
        int c = threadIdx.x;
        float v = bl[c];
        for (int k = 0; k < HID; ++k) v = fmaf(sg[k], Wl[k * N_CLS + c], v);
        out[g * N_CLS + c] = 1.0f / (1.0f + expf(-v));
    }
}

extern "C" void kernel_launch(void* const* d_in, const int* in_sizes, int n_in,
                              void* d_out, int out_size, void* d_ws, size_t ws_size,
                              hipStream_t stream) {
    const float* x     = (const float*)d_in[0];
    const int*   ei    = (const int*)d_in[1];
    const int*   batch = (const int*)d_in[2];
    const float* W1 = (const float*)d_in[3];  const float* b1 = (const float*)d_in[4];
    const float* W2 = (const float*)d_in[5];  const float* b2 = (const float*)d_in[6];
    const float* W3 = (const float*)d_in[7];  const float* b3 = (const float*)d_in[8];
    const float* W4 = (const float*)d_in[9];  const float* b4 = (const float*)d_in[10];
    const float* Wl = (const float*)d_in[11]; const float* bl = (const float*)d_in[12];
    float* out = (float*)d_out;

    const size_t EPAD = (size_t)N_EDGES + (size_t)NBUK * BUKPAD;   // 1.6M + 196*8192

    char* p = (char*)d_ws;
    auto alloc = [&](size_t bytes) { char* r = p; p += (bytes + 255) & ~(size_t)255; return (void*)r; };
    int*      C       = (int*)     alloc((size_t)NCHUNK * NBUK * 4);
    int*      Off     = (int*)     alloc((size_t)NCHUNK * NBUK * 4);
    int*      bbase   = (int*)     alloc((size_t)(NBUK + 1) * 4);
    unsigned* bkt     = (unsigned*)alloc((size_t)N_EDGES * 4);
    int*      deg     = (int*)     alloc((size_t)N_NODES * 4);
    int2*     rowBE   = (int2*)    alloc((size_t)N_NODES * 8);
    float*    dinv    = (float*)   alloc((size_t)N_NODES * 4);
    unsigned* edges   = (unsigned*)alloc(EPAD * 4);
    unsigned* hA      = (unsigned*)alloc((size_t)N_NODES * HID);      // fp8 ping
    unsigned* hC      = (unsigned*)alloc((size_t)N_NODES * HID);      // fp8 pong
    f16*      Wp      = (f16*)     alloc((size_t)3 * HID * HID * 2);
    f16*      Wp2 = Wp;
    f16*      Wp3 = Wp + HID * HID;
    f16*      Wp4 = Wp + 2 * HID * HID;

    const int* srcv = ei;              // edge_index[0]
    const int* dstv = ei + N_EDGES;    // edge_index[1]

    // CSR build: bucketed, no global atomics, padded-to-16 rows, closed-form pad bases
    k_bcp    <<<NCHUNK + 192, 256, 0, stream>>>(dstv, C, W2, W3, W4, Wp);
    k_bscan  <<<1, 256, 0, stream>>>(C, Off, bbase);
    k_scatter<<<NCHUNK, 256, 0, stream>>>(srcv, dstv, Off, bbase, bkt);
    k_build1 <<<NBUK, 256, 0, stream>>>(bkt, bbase, deg, dinv, rowBE);
    k_fill2  <<<NBUK, 256, 0, stream>>>(bkt, bbase, deg, dinv, rowBE, edges);

    // layer 1: fused wave-parallel Agg(x) + (Nx4)@(4x128) GEMM, fp8 out
    k_aggx1<<<N_NODES / 16, 256, 0, stream>>>((const float4*)x, rowBE, edges, dinv, W1, b1, hA);

    // layers 2..4: fused Agg (fp8 gather, full TLP) + MFMA GEMM (+bias, ReLU), fp8 out
    const int fgrid = N_NODES / 16;   // 6250, 1024-thread blocks
    k_aggemm8<<<fgrid, 1024, 0, stream>>>(hA, rowBE, edges, dinv, Wp2, b2, (unsigned char*)hC);
    k_aggemm8<<<fgrid, 1024, 0, stream>>>(hC, rowBE, edges, dinv, Wp3, b3, (unsigned char*)hA);
    k_aggemm8<<<fgrid, 1024, 0, stream>>>(hA, rowBE, edges, dinv, Wp4, b4, (unsigned char*)hC);

    // mean-pool + head, one block per graph
    k_poolh<<<N_GRAPH, 512, 0, stream>>>((const unsigned char*)hC, batch, Wl, bl, out);
}